// Round 2
// baseline (2009.159 us; speedup 1.0000x reference)
//
#include <hip/hip_runtime.h>
#include <math.h>

// 20-step attention LSTM decoder, N=128, H=512, L=256, V=64, fp32.
// Per step t:
//   k_attn2   (grid 256): block (n, half): flash-style partial attention over
//             128 keys (partial m,s,ctx) + fc/softmax for step t-1 on half==0.
//   k_layer<1>(grid 256): layer-0 gates = G[tok] + [ctx | h0] @ W^T, 2-way K-split
//             across thread halves; ctx combined from partials in A-staging; cell fused.
//   k_layer<0>(grid 256): layer-1 gates = b + [h0new | h1] @ W^T; cell fused.
// G[v][:] = b_ih0+b_hh0+emb[v]@Wih0[:, :512]^T precomputed once (V=64 << N*T).
// h ping-pongs in ws; c lives in d_out c_fin region; h copied out at the end.

#define HH 512
#define VV 64
#define NN 128
#define LL 256
#define TT 20
#define FH 2048  // 4*H
#define LP 33    // padded float4 row stride in LDS

__device__ __forceinline__ float sigf(float x) { return 1.0f / (1.0f + expf(-x)); }

__device__ __forceinline__ float wred_max(float x) {
#pragma unroll
  for (int o = 32; o > 0; o >>= 1) x = fmaxf(x, __shfl_xor(x, o));
  return x;
}
__device__ __forceinline__ float wred_sum(float x) {
#pragma unroll
  for (int o = 32; o > 0; o >>= 1) x += __shfl_xor(x, o);
  return x;
}

// Copy encoder states into working buffers. grid 128 x 256.
__global__ __launch_bounds__(256) void k_init(const float* __restrict__ eh,
                                              const float* __restrict__ ec,
                                              float* __restrict__ h0,
                                              float* __restrict__ h1,
                                              float* __restrict__ cfin) {
  int i = blockIdx.x * 256 + threadIdx.x;  // float4 index, 0..32767
  const int NH4 = NN * HH / 4;             // 16384
  float4 v = ((const float4*)eh)[i];
  if (i < NH4) ((float4*)h0)[i] = v;
  else         ((float4*)h1)[i - NH4] = v;
  ((float4*)cfin)[i] = ((const float4*)ec)[i];
}

// G[v][j] = b_ih0[j] + b_hh0[j] + dot(embedding[v], W_ih0[j][0:512])
__global__ __launch_bounds__(256) void k_pre(const float* __restrict__ emb,
                                             const float* __restrict__ Wih0,
                                             const float* __restrict__ bih0,
                                             const float* __restrict__ bhh0,
                                             float* __restrict__ G) {
  int v = threadIdx.x & 63, jj = threadIdx.x >> 6;
  int j = blockIdx.x * 4 + jj;
  const float4* e4 = (const float4*)(emb + (size_t)v * HH);
  const float4* w4 = (const float4*)(Wih0 + (size_t)j * (2 * HH));
  float acc = 0.f;
#pragma unroll 8
  for (int k = 0; k < HH / 4; ++k) {
    float4 a = e4[k], b = w4[k];
    acc += a.x * b.x + a.y * b.y + a.z * b.z + a.w * b.w;
  }
  G[(size_t)v * FH + j] = acc + bih0[j] + bhh0[j];
}

// grid 256: block b -> (n = b>>1, half = b&1). Partial attention over l-range
// [half*128, half*128+128): writes ctxp[half][n][:], ms[half][n]={m_p,s_p}.
// half==0 blocks also do fc+softmax for step tprev (reads same h1).
template <bool DO_FC>
__global__ __launch_bounds__(256) void k_attn2(
    const float* __restrict__ key, const float* __restrict__ value,
    const float* __restrict__ h1cur,
    const float* __restrict__ fc_w, const float* __restrict__ fc_b,
    float* __restrict__ probs, int tprev,
    float* __restrict__ ctxp, float* __restrict__ ms) {
  __shared__ float qs[HH];
  __shared__ float scp[2][128];
  __shared__ float att[128];
  __shared__ float lg[VV];
  __shared__ float red[4];
  int b = blockIdx.x, n = b >> 1, half = b & 1, tid = threadIdx.x;
  ((float2*)qs)[tid] = ((const float2*)(h1cur + (size_t)n * HH))[tid];
  __syncthreads();

  if (DO_FC && half == 0) {
    int v = tid >> 2, p = tid & 3;
    const float4* wr = (const float4*)(fc_w + (size_t)v * HH + p * 128);
    const float4* q4 = (const float4*)(qs + p * 128);
    float a = 0.f;
#pragma unroll 8
    for (int k = 0; k < 32; ++k) {
      float4 w = wr[k], q = q4[k];
      a += w.x * q.x + w.y * q.y + w.z * q.z + w.w * q.w;
    }
    a += __shfl_xor(a, 1);
    a += __shfl_xor(a, 2);
    if (p == 0) lg[v] = a + fc_b[v];
    __syncthreads();
    if (tid < VV) {
      float x = lg[tid];
      float m = wred_max(x);
      float e = expf(x - m);
      float s = wred_sum(e);
      probs[((size_t)n * TT + tprev) * VV + tid] = e / s;
    }
  }

  // scores: 2 threads per l (p = K-half of the 512-dim dot)
  const float SCALE = 0.044194173824159216f;  // 1/sqrt(512)
  int ll = tid & 127, p = tid >> 7;
  {
    const float4* kr =
        (const float4*)(key + ((size_t)n * LL + half * 128 + ll) * HH + p * 256);
    const float4* q4 = (const float4*)(qs + p * 256);
    float a = 0.f;
#pragma unroll 8
    for (int k = 0; k < 64; ++k) {
      float4 w = kr[k], q = q4[k];
      a += w.x * q.x + w.y * q.y + w.z * q.z + w.w * q.w;
    }
    scp[p][ll] = a;
  }
  __syncthreads();

  float x = 0.f;
  if (tid < 128) {
    x = (scp[0][tid] + scp[1][tid]) * SCALE;
    float m = wred_max(x);
    if ((tid & 63) == 0) red[tid >> 6] = m;
  }
  __syncthreads();
  float m_p = fmaxf(red[0], red[1]);
  if (tid < 128) {
    float e = expf(x - m_p);
    att[tid] = e;
    float s = wred_sum(e);
    if ((tid & 63) == 0) red[2 + (tid >> 6)] = s;
  }
  __syncthreads();
  if (tid == 0) {
    float2 v2 = {m_p, red[2] + red[3]};
    *(float2*)(ms + ((size_t)half * NN + n) * 2) = v2;
  }

  // partial ctx over this half's 128 l's; thread owns 2 consecutive h
  const float* vb = value + ((size_t)n * LL + half * 128) * HH + 2 * tid;
  float cx = 0.f, cy = 0.f;
#pragma unroll 4
  for (int l2 = 0; l2 < 128; ++l2) {
    float a2 = att[l2];
    float2 v2 = *(const float2*)(vb + (size_t)l2 * HH);
    cx += a2 * v2.x;
    cy += a2 * v2.y;
  }
  float2 o2 = {cx, cy};
  ((float2*)(ctxp + ((size_t)half * NN + n) * HH))[tid] = o2;
}

// fc+softmax for t=T-1 and copy final h states. grid 128.
__global__ __launch_bounds__(256) void k_final(
    const float* __restrict__ h1cur, const float* __restrict__ h0cur,
    const float* __restrict__ fc_w, const float* __restrict__ fc_b,
    float* __restrict__ probs, float* __restrict__ hfin) {
  __shared__ float qs[HH];
  __shared__ float lg[VV];
  int n = blockIdx.x, tid = threadIdx.x;
  ((float2*)qs)[tid] = ((const float2*)(h1cur + (size_t)n * HH))[tid];
  ((float2*)(hfin + (size_t)n * HH))[tid] =
      ((const float2*)(h0cur + (size_t)n * HH))[tid];
  ((float2*)(hfin + (size_t)(NN + n) * HH))[tid] =
      ((const float2*)(h1cur + (size_t)n * HH))[tid];
  __syncthreads();
  int v = tid >> 2, p = tid & 3;
  const float4* wr = (const float4*)(fc_w + (size_t)v * HH + p * 128);
  const float4* q4 = (const float4*)(qs + p * 128);
  float a = 0.f;
#pragma unroll 8
  for (int k = 0; k < 32; ++k) {
    float4 w = wr[k], q = q4[k];
    a += w.x * q.x + w.y * q.y + w.z * q.z + w.w * q.w;
  }
  a += __shfl_xor(a, 1);
  a += __shfl_xor(a, 2);
  if (p == 0) lg[v] = a + fc_b[v];
  __syncthreads();
  if (tid < VV) {
    float x = lg[tid];
    float m = wred_max(x);
    float e = expf(x - m);
    float s = wred_sum(e);
    probs[((size_t)n * TT + TT - 1) * VV + tid] = e / s;
  }
}

// Fused gate-GEMM + LSTM cell, 2-way K-split.
// grid 256 (sample-tile-major: bx = st*64 + jt), block 256 = 2 K-groups x 16 sg x 8 jl.
// Block: 32 samples x 8 jh x 4 gates. Group 0: x-segment (K=512, ctx-combine for
// layer 0), group 1: h-segment (K=512). LDS combine, then cell epilogue by group 0.
template <int COMBINE>
__global__ __launch_bounds__(256) void k_layer(
    const float* __restrict__ A0a, const float* __restrict__ A0b,
    const float* __restrict__ A1,
    const float* __restrict__ W0, int ws0, const float* __restrict__ W1,
    const int* __restrict__ word, const float* __restrict__ G,
    const float* __restrict__ bih, const float* __restrict__ bhh,
    const float* __restrict__ ms,
    float* __restrict__ cbuf, float* __restrict__ hnext, int t) {
  __shared__ float4 As[2 * 32 * LP];
  __shared__ float4 Ws[2 * 32 * LP];
  __shared__ float redb[128 * 9];
  __shared__ float sc0s[32], sc1s[32];

  int tid = threadIdx.x;
  int bx = blockIdx.x;
  int st = bx >> 6, jt = bx & 63;
  int s0 = st * 32, jh0 = jt * 8;
  int kg = tid >> 7;       // K-group
  int lt = tid & 127;
  int sg = lt >> 3, jl = lt & 7;
  int jh = jh0 + jl;

  if (COMBINE && tid < 32) {
    // per-sample flash-combine scales from the two attention partials
    int n = s0 + tid;
    float m0 = ms[(size_t)n * 2], sa = ms[(size_t)n * 2 + 1];
    float m1 = ms[(size_t)(NN + n) * 2], sb = ms[(size_t)(NN + n) * 2 + 1];
    float m = fmaxf(m0, m1);
    float e0 = expf(m0 - m), e1 = expf(m1 - m);
    float S = sa * e0 + sb * e1;
    sc0s[tid] = e0 / S;
    sc1s[tid] = e1 / S;
  }

  float acc[2][4];
  if (kg == 0) {
    if (COMBINE) {
      int sa = s0 + sg * 2, sb = sa + 1;
      int ta = (t == 0) ? 0 : (word[sa * TT + t - 1] & 63);
      int tb = (t == 0) ? 0 : (word[sb * TT + t - 1] & 63);
#pragma unroll
      for (int g = 0; g < 4; ++g) {
        acc[0][g] = G[(size_t)ta * FH + g * HH + jh];
        acc[1][g] = G[(size_t)tb * FH + g * HH + jh];
      }
    } else {
#pragma unroll
      for (int g = 0; g < 4; ++g) {
        float b = bih[g * HH + jh] + bhh[g * HH + jh];
        acc[0][g] = b;
        acc[1][g] = b;
      }
    }
  } else {
#pragma unroll
    for (int g = 0; g < 4; ++g) { acc[0][g] = 0.f; acc[1][g] = 0.f; }
  }

  const float* Wb = kg ? W1 : W0;
  int wst = kg ? HH : ws0;
  float4* Asg = As + kg * (32 * LP);
  float4* Wsg = Ws + kg * (32 * LP);

  for (int kc = 0; kc < HH; kc += 128) {
    __syncthreads();
    // stage: this group's A-tile (32x32 f4) and W-tile (32x32 f4)
#pragma unroll
    for (int i = 0; i < 8; ++i) {
      int fi = lt + i * 128;
      int r = fi >> 5, c4 = fi & 31;
      float4 v;
      if (kg == 0) {
        if (COMBINE) {
          float4 u0 = *((const float4*)(A0a + (size_t)(s0 + r) * HH + kc) + c4);
          float4 u1 = *((const float4*)(A0b + (size_t)(s0 + r) * HH + kc) + c4);
          float a0 = sc0s[r], a1 = sc1s[r];
          v.x = a0 * u0.x + a1 * u1.x;
          v.y = a0 * u0.y + a1 * u1.y;
          v.z = a0 * u0.z + a1 * u1.z;
          v.w = a0 * u0.w + a1 * u1.w;
        } else {
          v = *((const float4*)(A0a + (size_t)(s0 + r) * HH + kc) + c4);
        }
      } else {
        v = *((const float4*)(A1 + (size_t)(s0 + r) * HH + kc) + c4);
      }
      Asg[r * LP + c4] = v;
      int g = r >> 3, jj = r & 7;
      Wsg[r * LP + c4] =
          *((const float4*)(Wb + (size_t)(g * HH + jh0 + jj) * wst + kc) + c4);
    }
    __syncthreads();
    const float4* Ar0 = Asg + (sg * 2) * LP;
    const float4* Ar1 = Asg + (sg * 2 + 1) * LP;
    const float4* Wr0 = Wsg + (0 * 8 + jl) * LP;
    const float4* Wr1 = Wsg + (1 * 8 + jl) * LP;
    const float4* Wr2 = Wsg + (2 * 8 + jl) * LP;
    const float4* Wr3 = Wsg + (3 * 8 + jl) * LP;
#pragma unroll 8
    for (int kq = 0; kq < 32; ++kq) {
      float4 a0 = Ar0[kq], a1 = Ar1[kq];
      float4 w;
      w = Wr0[kq];
      acc[0][0] += a0.x * w.x + a0.y * w.y + a0.z * w.z + a0.w * w.w;
      acc[1][0] += a1.x * w.x + a1.y * w.y + a1.z * w.z + a1.w * w.w;
      w = Wr1[kq];
      acc[0][1] += a0.x * w.x + a0.y * w.y + a0.z * w.z + a0.w * w.w;
      acc[1][1] += a1.x * w.x + a1.y * w.y + a1.z * w.z + a1.w * w.w;
      w = Wr2[kq];
      acc[0][2] += a0.x * w.x + a0.y * w.y + a0.z * w.z + a0.w * w.w;
      acc[1][2] += a1.x * w.x + a1.y * w.y + a1.z * w.z + a1.w * w.w;
      w = Wr3[kq];
      acc[0][3] += a0.x * w.x + a0.y * w.y + a0.z * w.z + a0.w * w.w;
      acc[1][3] += a1.x * w.x + a1.y * w.y + a1.z * w.z + a1.w * w.w;
    }
  }

  __syncthreads();
  if (kg == 1) {
#pragma unroll
    for (int si = 0; si < 2; ++si)
#pragma unroll
      for (int g = 0; g < 4; ++g) redb[lt * 9 + si * 4 + g] = acc[si][g];
  }
  __syncthreads();
  if (kg == 0) {
#pragma unroll
    for (int si = 0; si < 2; ++si) {
#pragma unroll
      for (int g = 0; g < 4; ++g) acc[si][g] += redb[lt * 9 + si * 4 + g];
      int s = s0 + sg * 2 + si;
      float i_ = acc[si][0], f_ = acc[si][1], g_ = acc[si][2], o_ = acc[si][3];
      float* cp = cbuf + (size_t)s * HH + jh;
      float c_old = *cp;
      float cn = sigf(f_) * c_old + sigf(i_) * tanhf(g_);
      *cp = cn;
      hnext[(size_t)s * HH + jh] = sigf(o_) * tanhf(cn);
    }
  }
}

extern "C" void kernel_launch(void* const* d_in, const int* in_sizes, int n_in,
                              void* d_out, int out_size, void* d_ws, size_t ws_size,
                              hipStream_t stream) {
  const float* key   = (const float*)d_in[0];
  const float* value = (const float*)d_in[1];
  const float* eh    = (const float*)d_in[2];
  const float* ec    = (const float*)d_in[3];
  const int*   word  = (const int*)d_in[4];
  const float* emb   = (const float*)d_in[5];
  const float* Wih0  = (const float*)d_in[6];
  const float* Whh0  = (const float*)d_in[7];
  const float* bih0  = (const float*)d_in[8];
  const float* bhh0  = (const float*)d_in[9];
  const float* Wih1  = (const float*)d_in[10];
  const float* Whh1  = (const float*)d_in[11];
  const float* bih1  = (const float*)d_in[12];
  const float* bhh1  = (const float*)d_in[13];
  const float* fcw   = (const float*)d_in[14];
  const float* fcb   = (const float*)d_in[15];

  float* out   = (float*)d_out;
  float* probs = out;                         // (N, T, V)
  float* hfin  = out + (size_t)NN * TT * VV;  // (2, N, H)
  float* cfin  = hfin + 2 * (size_t)NN * HH;  // (2, N, H) -- live c state

  float* ws   = (float*)d_ws;
  float* G    = ws;                            // 64 * 2048
  float* ctxp = G + (size_t)VV * FH;           // 2 * 128 * 512 (partials)
  float* ms   = ctxp + 2 * (size_t)NN * HH;    // 2 * 128 * 2
  float* h0a  = ms + 2 * (size_t)NN * 2;
  float* h0b  = h0a + (size_t)NN * HH;
  float* h1a  = h0b + (size_t)NN * HH;
  float* h1b  = h1a + (size_t)NN * HH;

  k_init<<<128, 256, 0, stream>>>(eh, ec, h0a, h1a, cfin);
  k_pre<<<512, 256, 0, stream>>>(emb, Wih0, bih0, bhh0, G);

  float* h0c = h0a; float* h0n = h0b;
  float* h1c = h1a; float* h1n = h1b;

  for (int t = 0; t < TT; ++t) {
    if (t == 0)
      k_attn2<false><<<256, 256, 0, stream>>>(key, value, h1c, fcw, fcb,
                                              probs, 0, ctxp, ms);
    else
      k_attn2<true><<<256, 256, 0, stream>>>(key, value, h1c, fcw, fcb,
                                             probs, t - 1, ctxp, ms);

    k_layer<1><<<256, 256, 0, stream>>>(
        ctxp, ctxp + (size_t)NN * HH, h0c, Wih0 + HH, 2 * HH, Whh0,
        word, G, bih0, bhh0, ms, cfin, h0n, t);
    k_layer<0><<<256, 256, 0, stream>>>(
        h0n, (const float*)nullptr, h1c, Wih1, HH, Whh1,
        word, G, bih1, bhh1, ms, cfin + (size_t)NN * HH, h1n, t);

    float* tmp;
    tmp = h0c; h0c = h0n; h0n = tmp;
    tmp = h1c; h1c = h1n; h1n = tmp;
  }

  k_final<<<128, 256, 0, stream>>>(h1c, h0c, fcw, fcb, probs, hfin);
}

// Round 3
// 1309.625 us; speedup vs baseline: 1.5341x; 1.5341x over previous
//
#include <hip/hip_runtime.h>
#include <math.h>

// 20-step attention LSTM decoder, N=128, H=512, L=256, V=64, fp32 in/out.
// Gate GEMMs run on MFMA (bf16 3-term split = fp32-accurate):
//   C = Ah*Wh + Al*Wh + Ah*Wl  (dropped Al*Wl ~ 2^-18 rel)
// W rows are consumed in permuted order row' = jh*4 + gate so each block owns
// all 4 gates of its jh's -> fused LSTM cell epilogue stays in-block.
// G[v][jh*4+g] = biases + emb[v]@Wih0_x precomputed once (V=64 << N*T).

#define HH 512
#define VV 64
#define NN 128
#define LL 256
#define TT 20
#define FH 2048  // 4*H
#define LKP 136  // LDS K stride in bf16 elems (128 + 8 pad)
#define CSP 36   // C LDS row stride in f32

typedef __attribute__((ext_vector_type(8))) short bf16x8;
typedef __attribute__((ext_vector_type(4))) float f32x4;

__device__ __forceinline__ float sigf(float x) { return 1.0f / (1.0f + expf(-x)); }

__device__ __forceinline__ float wred_max(float x) {
#pragma unroll
  for (int o = 32; o > 0; o >>= 1) x = fmaxf(x, __shfl_xor(x, o));
  return x;
}
__device__ __forceinline__ float wred_sum(float x) {
#pragma unroll
  for (int o = 32; o > 0; o >>= 1) x += __shfl_xor(x, o);
  return x;
}

// Copy encoder states into working buffers. grid 128 x 256.
__global__ __launch_bounds__(256) void k_init(const float* __restrict__ eh,
                                              const float* __restrict__ ec,
                                              float* __restrict__ h0,
                                              float* __restrict__ h1,
                                              float* __restrict__ cfin) {
  int i = blockIdx.x * 256 + threadIdx.x;  // float4 index
  const int NH4 = NN * HH / 4;
  float4 v = ((const float4*)eh)[i];
  if (i < NH4) ((float4*)h0)[i] = v;
  else         ((float4*)h1)[i - NH4] = v;
  ((float4*)cfin)[i] = ((const float4*)ec)[i];
}

// G[v][jh*4+g] = b_ih0[j]+b_hh0[j] + dot(emb[v], W_ih0[j][0:512]), j = g*512+jh
__global__ __launch_bounds__(256) void k_pre(const float* __restrict__ emb,
                                             const float* __restrict__ Wih0,
                                             const float* __restrict__ bih0,
                                             const float* __restrict__ bhh0,
                                             float* __restrict__ G) {
  int v = threadIdx.x & 63, jj = threadIdx.x >> 6;
  int j = blockIdx.x * 4 + jj;
  const float4* e4 = (const float4*)(emb + (size_t)v * HH);
  const float4* w4 = (const float4*)(Wih0 + (size_t)j * (2 * HH));
  float acc = 0.f;
#pragma unroll 8
  for (int k = 0; k < HH / 4; ++k) {
    float4 a = e4[k], b = w4[k];
    acc += a.x * b.x + a.y * b.y + a.z * b.z + a.w * b.w;
  }
  G[(size_t)v * FH + ((j & 511) << 2) + (j >> 9)] = acc + bih0[j] + bhh0[j];
}

// grid 256: block b -> (n = b>>1, half = b&1). Partial attention over 128 keys;
// writes ctxp[half][n][:], ms[half][n]={m_p,s_p}. half==0 also fc+softmax(tprev).
template <bool DO_FC>
__global__ __launch_bounds__(256) void k_attn2(
    const float* __restrict__ key, const float* __restrict__ value,
    const float* __restrict__ h1cur,
    const float* __restrict__ fc_w, const float* __restrict__ fc_b,
    float* __restrict__ probs, int tprev,
    float* __restrict__ ctxp, float* __restrict__ ms) {
  __shared__ float qs[HH];
  __shared__ float scp[2][128];
  __shared__ float att[128];
  __shared__ float lg[VV];
  __shared__ float red[4];
  int b = blockIdx.x, n = b >> 1, half = b & 1, tid = threadIdx.x;
  ((float2*)qs)[tid] = ((const float2*)(h1cur + (size_t)n * HH))[tid];
  __syncthreads();

  if (DO_FC && half == 0) {
    int v = tid >> 2, p = tid & 3;
    const float4* wr = (const float4*)(fc_w + (size_t)v * HH + p * 128);
    const float4* q4 = (const float4*)(qs + p * 128);
    float a = 0.f;
#pragma unroll 8
    for (int k = 0; k < 32; ++k) {
      float4 w = wr[k], q = q4[k];
      a += w.x * q.x + w.y * q.y + w.z * q.z + w.w * q.w;
    }
    a += __shfl_xor(a, 1);
    a += __shfl_xor(a, 2);
    if (p == 0) lg[v] = a + fc_b[v];
    __syncthreads();
    if (tid < VV) {
      float x = lg[tid];
      float m = wred_max(x);
      float e = expf(x - m);
      float s = wred_sum(e);
      probs[((size_t)n * TT + tprev) * VV + tid] = e / s;
    }
  }

  const float SCALE = 0.044194173824159216f;  // 1/sqrt(512)
  int ll = tid & 127, p = tid >> 7;
  {
    const float4* kr =
        (const float4*)(key + ((size_t)n * LL + half * 128 + ll) * HH + p * 256);
    const float4* q4 = (const float4*)(qs + p * 256);
    float a = 0.f;
#pragma unroll 8
    for (int k = 0; k < 64; ++k) {
      float4 w = kr[k], q = q4[k];
      a += w.x * q.x + w.y * q.y + w.z * q.z + w.w * q.w;
    }
    scp[p][ll] = a;
  }
  __syncthreads();

  float x = 0.f;
  if (tid < 128) {
    x = (scp[0][tid] + scp[1][tid]) * SCALE;
    float m = wred_max(x);
    if ((tid & 63) == 0) red[tid >> 6] = m;
  }
  __syncthreads();
  float m_p = fmaxf(red[0], red[1]);
  if (tid < 128) {
    float e = expf(x - m_p);
    att[tid] = e;
    float s = wred_sum(e);
    if ((tid & 63) == 0) red[2 + (tid >> 6)] = s;
  }
  __syncthreads();
  if (tid == 0) {
    float2 v2 = {m_p, red[2] + red[3]};
    *(float2*)(ms + ((size_t)half * NN + n) * 2) = v2;
  }

  const float* vb = value + ((size_t)n * LL + half * 128) * HH + 2 * tid;
  float cx = 0.f, cy = 0.f;
#pragma unroll 4
  for (int l2 = 0; l2 < 128; ++l2) {
    float a2 = att[l2];
    float2 v2 = *(const float2*)(vb + (size_t)l2 * HH);
    cx += a2 * v2.x;
    cy += a2 * v2.y;
  }
  float2 o2 = {cx, cy};
  ((float2*)(ctxp + ((size_t)half * NN + n) * HH))[tid] = o2;
}

// fc+softmax for t=T-1 and copy final h states. grid 128.
__global__ __launch_bounds__(256) void k_final(
    const float* __restrict__ h1cur, const float* __restrict__ h0cur,
    const float* __restrict__ fc_w, const float* __restrict__ fc_b,
    float* __restrict__ probs, float* __restrict__ hfin) {
  __shared__ float qs[HH];
  __shared__ float lg[VV];
  int n = blockIdx.x, tid = threadIdx.x;
  ((float2*)qs)[tid] = ((const float2*)(h1cur + (size_t)n * HH))[tid];
  ((float2*)(hfin + (size_t)n * HH))[tid] =
      ((const float2*)(h0cur + (size_t)n * HH))[tid];
  ((float2*)(hfin + (size_t)(NN + n) * HH))[tid] =
      ((const float2*)(h1cur + (size_t)n * HH))[tid];
  __syncthreads();
  int v = tid >> 2, p = tid & 3;
  const float4* wr = (const float4*)(fc_w + (size_t)v * HH + p * 128);
  const float4* q4 = (const float4*)(qs + p * 128);
  float a = 0.f;
#pragma unroll 8
  for (int k = 0; k < 32; ++k) {
    float4 w = wr[k], q = q4[k];
    a += w.x * q.x + w.y * q.y + w.z * q.z + w.w * q.w;
  }
  a += __shfl_xor(a, 1);
  a += __shfl_xor(a, 2);
  if (p == 0) lg[v] = a + fc_b[v];
  __syncthreads();
  if (tid < VV) {
    float x = lg[tid];
    float m = wred_max(x);
    float e = expf(x - m);
    float s = wred_sum(e);
    probs[((size_t)n * TT + TT - 1) * VV + tid] = e / s;
  }
}

// MFMA gate-GEMM + fused LSTM cell.
// grid 256: mt = bx&3 (sample tile of 32), nt = bx>>2 (32 permuted gate rows).
// Block 256 thr = 4 waves, wave (wm,wn) does 16x16 C via mfma_f32_16x16x32_bf16,
// 3-term bf16 split for fp32 accuracy. K = 1024 = [x-seg 512 | h-seg 512],
// staged in 8 chunks of 128 with a 1-deep register pipeline.
template <int COMBINE>
__global__ __launch_bounds__(256) void k_gemm(
    const float* __restrict__ Ax0, const float* __restrict__ Ax1,
    const float* __restrict__ Ahh,
    const float* __restrict__ W0, int ws0,
    const float* __restrict__ W1, int ws1,
    const int* __restrict__ word, const float* __restrict__ G,
    const float* __restrict__ bih, const float* __restrict__ bhh,
    const float* __restrict__ ms,
    float* __restrict__ cbuf, float* __restrict__ hnext, int t) {
  __shared__ __align__(16) unsigned short AhS[32 * LKP];
  __shared__ __align__(16) unsigned short AlS[32 * LKP];
  __shared__ __align__(16) unsigned short WhS[32 * LKP];
  __shared__ __align__(16) unsigned short WlS[32 * LKP];
  __shared__ float sc0s[32], sc1s[32];
  __shared__ __align__(16) float Cs[32 * CSP];

  int tid = threadIdx.x;
  int mt = blockIdx.x & 3, nt = blockIdx.x >> 2;
  int s0 = mt * 32, n0 = nt * 32;

  // staging coords: row r (0..31), k-quad kq -> 16 floats at kk
  int r = tid >> 3, kq = tid & 7, kk = kq * 16;
  int rowp = n0 + r;                 // permuted W row
  int jrow = (rowp & 3) * 512 + (rowp >> 2);  // original W row

  if (COMBINE && tid < 32) {
    int n = s0 + tid;
    float m0 = ms[2 * n], sa = ms[2 * n + 1];
    float m1 = ms[2 * (NN + n)], sb = ms[2 * (NN + n) + 1];
    float m = fmaxf(m0, m1);
    float e0 = expf(m0 - m), e1 = expf(m1 - m);
    float S = sa * e0 + sb * e1;
    sc0s[tid] = e0 / S;
    sc1s[tid] = e1 / S;
  }

  float4 aR0[4], aR1[4], wRg[4];

  auto LOADC = [&](int c) {
    int k0 = c * 128;
    if (k0 < 512) {
      const float4* p0 = (const float4*)(Ax0 + (size_t)(s0 + r) * HH + k0 + kk);
#pragma unroll
      for (int i = 0; i < 4; ++i) aR0[i] = p0[i];
      if (COMBINE) {
        const float4* p1 = (const float4*)(Ax1 + (size_t)(s0 + r) * HH + k0 + kk);
#pragma unroll
        for (int i = 0; i < 4; ++i) aR1[i] = p1[i];
      }
      const float4* wp = (const float4*)(W0 + (size_t)jrow * ws0 + k0 + kk);
#pragma unroll
      for (int i = 0; i < 4; ++i) wRg[i] = wp[i];
    } else {
      const float4* p0 =
          (const float4*)(Ahh + (size_t)(s0 + r) * HH + (k0 - 512) + kk);
#pragma unroll
      for (int i = 0; i < 4; ++i) aR0[i] = p0[i];
      const float4* wp = (const float4*)(W1 + (size_t)jrow * ws1 + (k0 - 512) + kk);
#pragma unroll
      for (int i = 0; i < 4; ++i) wRg[i] = wp[i];
    }
  };

  auto STOREC = [&](int c) {
    int k0 = c * 128;
    bool cmb = COMBINE && (k0 < 512);
    float sa = cmb ? sc0s[r] : 0.f, sb = cmb ? sc1s[r] : 0.f;
#pragma unroll
    for (int i = 0; i < 2; ++i) {
      float xa[8], xw[8];
      float4 u0 = aR0[2 * i], u1 = aR0[2 * i + 1];
      xa[0] = u0.x; xa[1] = u0.y; xa[2] = u0.z; xa[3] = u0.w;
      xa[4] = u1.x; xa[5] = u1.y; xa[6] = u1.z; xa[7] = u1.w;
      if (cmb) {
        float4 v0 = aR1[2 * i], v1 = aR1[2 * i + 1];
        xa[0] = sa * xa[0] + sb * v0.x; xa[1] = sa * xa[1] + sb * v0.y;
        xa[2] = sa * xa[2] + sb * v0.z; xa[3] = sa * xa[3] + sb * v0.w;
        xa[4] = sa * xa[4] + sb * v1.x; xa[5] = sa * xa[5] + sb * v1.y;
        xa[6] = sa * xa[6] + sb * v1.z; xa[7] = sa * xa[7] + sb * v1.w;
      }
      float4 w0 = wRg[2 * i], w1 = wRg[2 * i + 1];
      xw[0] = w0.x; xw[1] = w0.y; xw[2] = w0.z; xw[3] = w0.w;
      xw[4] = w1.x; xw[5] = w1.y; xw[6] = w1.z; xw[7] = w1.w;
      bf16x8 ah, al, wh, wl;
#pragma unroll
      for (int j = 0; j < 8; ++j) {
        unsigned int u = __float_as_uint(xa[j]);
        unsigned int hb = (u + 0x7FFFu + ((u >> 16) & 1u)) & 0xFFFF0000u;
        ah[j] = (short)(hb >> 16);
        float lo = xa[j] - __uint_as_float(hb);
        unsigned int ul = __float_as_uint(lo);
        al[j] = (short)((ul + 0x7FFFu + ((ul >> 16) & 1u)) >> 16);
        u = __float_as_uint(xw[j]);
        hb = (u + 0x7FFFu + ((u >> 16) & 1u)) & 0xFFFF0000u;
        wh[j] = (short)(hb >> 16);
        lo = xw[j] - __uint_as_float(hb);
        ul = __float_as_uint(lo);
        wl[j] = (short)((ul + 0x7FFFu + ((ul >> 16) & 1u)) >> 16);
      }
      int off = r * LKP + kk + i * 8;
      *(bf16x8*)(AhS + off) = ah;
      *(bf16x8*)(AlS + off) = al;
      *(bf16x8*)(WhS + off) = wh;
      *(bf16x8*)(WlS + off) = wl;
    }
  };

  f32x4 acc0 = {0.f, 0.f, 0.f, 0.f};
  f32x4 acc1 = {0.f, 0.f, 0.f, 0.f};
  f32x4 acc2 = {0.f, 0.f, 0.f, 0.f};
  int lane = tid & 63, wv = tid >> 6;
  int wm = wv >> 1, wn = wv & 1;
  int aoff = (wm * 16 + (lane & 15)) * LKP;
  int woff = (wn * 16 + (lane & 15)) * LKP;
  int kb = (lane >> 4) * 8;

  LOADC(0);
  __syncthreads();  // scales visible before first STOREC use
  for (int c = 0; c < 8; ++c) {
    if (c) __syncthreads();  // prev chunk's frag reads done
    STOREC(c);
    __syncthreads();
    if (c < 7) LOADC(c + 1);  // overlap next loads with MFMA phase
#pragma unroll
    for (int ks = 0; ks < 4; ++ks) {
      int ko = kb + ks * 32;
      bf16x8 ah = *(const bf16x8*)(AhS + aoff + ko);
      bf16x8 al = *(const bf16x8*)(AlS + aoff + ko);
      bf16x8 wh = *(const bf16x8*)(WhS + woff + ko);
      bf16x8 wl = *(const bf16x8*)(WlS + woff + ko);
      acc0 = __builtin_amdgcn_mfma_f32_16x16x32_bf16(ah, wh, acc0, 0, 0, 0);
      acc1 = __builtin_amdgcn_mfma_f32_16x16x32_bf16(al, wh, acc1, 0, 0, 0);
      acc2 = __builtin_amdgcn_mfma_f32_16x16x32_bf16(ah, wl, acc2, 0, 0, 0);
    }
  }

  // epilogue: C -> LDS remap -> fused LSTM cell
  __syncthreads();
  f32x4 cv = acc0 + acc1;
  cv = cv + acc2;
  int crow = wm * 16 + (lane >> 4) * 4, ccol = wn * 16 + (lane & 15);
#pragma unroll
  for (int q = 0; q < 4; ++q) Cs[(crow + q) * CSP + ccol] = cv[q];
  __syncthreads();
  int s_l = tid >> 3, jh_l = tid & 7;
  int s = s0 + s_l, jh = nt * 8 + jh_l;
  f32x4 c4 = *(const f32x4*)(Cs + s_l * CSP + jh_l * 4);
  if (COMBINE) {
    int tok = (t == 0) ? 0 : (word[s * TT + t - 1] & 63);
    f32x4 g4 = *(const f32x4*)(G + (size_t)tok * FH + jh * 4);
    c4 = c4 + g4;
  } else {
    c4[0] += bih[jh] + bhh[jh];
    c4[1] += bih[512 + jh] + bhh[512 + jh];
    c4[2] += bih[1024 + jh] + bhh[1024 + jh];
    c4[3] += bih[1536 + jh] + bhh[1536 + jh];
  }
  float c_old = cbuf[(size_t)s * HH + jh];
  float cn = sigf(c4[1]) * c_old + sigf(c4[0]) * tanhf(c4[2]);
  cbuf[(size_t)s * HH + jh] = cn;
  hnext[(size_t)s * HH + jh] = sigf(c4[3]) * tanhf(cn);
}

extern "C" void kernel_launch(void* const* d_in, const int* in_sizes, int n_in,
                              void* d_out, int out_size, void* d_ws, size_t ws_size,
                              hipStream_t stream) {
  const float* key   = (const float*)d_in[0];
  const float* value = (const float*)d_in[1];
  const float* eh    = (const float*)d_in[2];
  const float* ec    = (const float*)d_in[3];
  const int*   word  = (const int*)d_in[4];
  const float* emb   = (const float*)d_in[5];
  const float* Wih0  = (const float*)d_in[6];
  const float* Whh0  = (const float*)d_in[7];
  const float* bih0  = (const float*)d_in[8];
  const float* bhh0  = (const float*)d_in[9];
  const float* Wih1  = (const float*)d_in[10];
  const float* Whh1  = (const float*)d_in[11];
  const float* bih1  = (const float*)d_in[12];
  const float* bhh1  = (const float*)d_in[13];
  const float* fcw   = (const float*)d_in[14];
  const float* fcb   = (const float*)d_in[15];

  float* out   = (float*)d_out;
  float* probs = out;                         // (N, T, V)
  float* hfin  = out + (size_t)NN * TT * VV;  // (2, N, H)
  float* cfin  = hfin + 2 * (size_t)NN * HH;  // (2, N, H) -- live c state

  float* ws   = (float*)d_ws;
  float* G    = ws;                          // 64 * 2048 (permuted jh*4+g)
  float* ctxp = G + (size_t)VV * FH;         // 2 * 128 * 512 partial ctx
  float* ms   = ctxp + 2 * (size_t)NN * HH;  // 2 * 128 * {m,s}
  float* h0a  = ms + 2 * (size_t)NN * 2;
  float* h0b  = h0a + (size_t)NN * HH;
  float* h1a  = h0b + (size_t)NN * HH;
  float* h1b  = h1a + (size_t)NN * HH;

  k_init<<<128, 256, 0, stream>>>(eh, ec, h0a, h1a, cfin);
  k_pre<<<512, 256, 0, stream>>>(emb, Wih0, bih0, bhh0, G);

  float* h0c = h0a; float* h0n = h0b;
  float* h1c = h1a; float* h1n = h1b;

  for (int t = 0; t < TT; ++t) {
    if (t == 0)
      k_attn2<false><<<256, 256, 0, stream>>>(key, value, h1c, fcw, fcb,
                                              probs, 0, ctxp, ms);
    else
      k_attn2<true><<<256, 256, 0, stream>>>(key, value, h1c, fcw, fcb,
                                             probs, t - 1, ctxp, ms);

    k_gemm<1><<<256, 256, 0, stream>>>(
        ctxp, ctxp + (size_t)NN * HH, h0c, Wih0 + 512, 2 * HH, Whh0, HH,
        word, G, bih0, bhh0, ms, cfin, h0n, t);
    k_gemm<0><<<256, 256, 0, stream>>>(
        h0n, (const float*)nullptr, h1c, Wih1, HH, Whh1, HH,
        word, G, bih1, bhh1, ms, cfin + (size_t)NN * HH, h1n, t);

    float* tmp;
    tmp = h0c; h0c = h0n; h0n = tmp;
    tmp = h1c; h1c = h1n; h1n = tmp;
  }

  k_final<<<128, 256, 0, stream>>>(h1c, h0c, fcw, fcb, probs, hfin);
}